// Round 1
// baseline (1060.596 us; speedup 1.0000x reference)
//
#include <hip/hip_runtime.h>
#include <math.h>

#define ALPHA_C 0.1f

__device__ __forceinline__ float readlane_f(float v, int l) {
    return __int_as_float(__builtin_amdgcn_readlane(__float_as_int(v), l));
}

// ---------------- CSR build ----------------
__global__ void k_hist(const int* __restrict__ col, int E, int* __restrict__ count) {
    int i = blockIdx.x * blockDim.x + threadIdx.x;
    if (i < E) atomicAdd(&count[col[i]], 1);
}

__global__ void k_dinv(const int* __restrict__ count, float* __restrict__ dinv, int N) {
    int i = blockIdx.x * blockDim.x + threadIdx.x;
    if (i < N) dinv[i] = rsqrtf(1.0f + (float)count[i]);  // +1 = self loop
}

__global__ void k_scan1(const int* __restrict__ count, int N,
                        int* __restrict__ offs, int* __restrict__ bsum) {
    __shared__ int s[256];
    int tid = threadIdx.x;
    int gid = blockIdx.x * 256 + tid;
    int v = (gid < N) ? count[gid] : 0;
    s[tid] = v;
    __syncthreads();
    for (int d = 1; d < 256; d <<= 1) {
        int t = (tid >= d) ? s[tid - d] : 0;
        __syncthreads();
        s[tid] += t;
        __syncthreads();
    }
    if (gid < N) offs[gid] = s[tid] - v;      // block-local exclusive
    if (tid == 255) bsum[blockIdx.x] = s[255];
}

__global__ void k_scan2(int* __restrict__ bsum, int B) {
    __shared__ int s[512];
    int tid = threadIdx.x;
    int v = (tid < B) ? bsum[tid] : 0;
    s[tid] = v;
    __syncthreads();
    for (int d = 1; d < 512; d <<= 1) {
        int t = (tid >= d) ? s[tid - d] : 0;
        __syncthreads();
        s[tid] += t;
        __syncthreads();
    }
    if (tid < B) bsum[tid] = s[tid] - v;      // exclusive block bases
}

__global__ void k_scan3(int* __restrict__ offs, const int* __restrict__ bsum, int N, int E) {
    int gid = blockIdx.x * blockDim.x + threadIdx.x;
    if (gid < N) offs[gid] += bsum[blockIdx.x];
    if (gid == 0) offs[N] = E;
}

__global__ void k_scatter(const int* __restrict__ row, const int* __restrict__ col,
                          const int* __restrict__ offs, int* __restrict__ cursor,
                          int* __restrict__ srcarr, int E) {
    int e = blockIdx.x * blockDim.x + threadIdx.x;
    if (e < E) {
        int c = col[e];
        int pos = offs[c] + atomicAdd(&cursor[c], 1);
        srcarr[pos] = row[e];
    }
}

// ---------------- input transform: h0 = relu(x @ W_in + b_in) ----------------
__global__ void k_in(const float* __restrict__ x, const float* __restrict__ Win,
                     const float* __restrict__ bin, float* __restrict__ h0, int N) {
    int lane = threadIdx.x & 63;
    int wave = (blockIdx.x * blockDim.x + threadIdx.x) >> 6;
    int nwaves = (gridDim.x * blockDim.x) >> 6;
    float wreg[17];
#pragma unroll
    for (int k = 0; k < 17; ++k) wreg[k] = Win[k * 64 + lane];
    float breg = bin[lane];
    for (int i = wave; i < N; i += nwaves) {
        float xv = (lane < 17) ? x[i * 17 + lane] : 0.0f;
        float acc = breg;
#pragma unroll
        for (int k = 0; k < 17; ++k) acc += readlane_f(xv, k) * wreg[k];
        h0[(size_t)i * 64 + lane] = fmaxf(acc, 0.0f);
    }
}

// ---------------- support = (1-b)(1-a) h + b * (h @ W1) ----------------
__global__ void k_support(const float* __restrict__ h, const float* __restrict__ W1,
                          float beta, float* __restrict__ sup, int N) {
    int lane = threadIdx.x & 63;
    int wave = (blockIdx.x * blockDim.x + threadIdx.x) >> 6;
    int nwaves = (gridDim.x * blockDim.x) >> 6;
    float wreg[64];  // column `lane` of W1 held in VGPRs: no LDS in inner loop
#pragma unroll
    for (int k = 0; k < 64; ++k) wreg[k] = W1[k * 64 + lane];
    float c1 = (1.0f - beta) * (1.0f - ALPHA_C);
    for (int i = wave; i < N; i += nwaves) {
        float hv = h[(size_t)i * 64 + lane];
        float acc = 0.0f;
#pragma unroll
        for (int k = 0; k < 64; ++k) acc += readlane_f(hv, k) * wreg[k];
        sup[(size_t)i * 64 + lane] = c1 * hv + beta * acc;
    }
}

// ---- agg: h = relu( selfloop + edge gather + (1-b)a h0 + b (h0 @ W2) ) ----
__global__ void k_agg(const float* __restrict__ sup, const float* __restrict__ h0,
                      const float* __restrict__ W2, const float* __restrict__ dinv,
                      const int* __restrict__ offs, const int* __restrict__ srcarr,
                      float beta, float* __restrict__ h, int N) {
    int lane = threadIdx.x & 63;
    int wave = (blockIdx.x * blockDim.x + threadIdx.x) >> 6;
    int nwaves = (gridDim.x * blockDim.x) >> 6;
    float wreg[64];  // column of W2
#pragma unroll
    for (int k = 0; k < 64; ++k) wreg[k] = W2[k * 64 + lane];
    float c2 = (1.0f - beta) * ALPHA_C;
    for (int i = wave; i < N; i += nwaves) {
        float h0v = h0[(size_t)i * 64 + lane];
        float acc = 0.0f;
#pragma unroll
        for (int k = 0; k < 64; ++k) acc += readlane_f(h0v, k) * wreg[k];
        float di = dinv[i];
        float res = c2 * h0v + beta * acc + di * di * sup[(size_t)i * 64 + lane];
        int e0 = offs[i], e1 = offs[i + 1];
        int sNext = (e0 < e1) ? srcarr[e0] : 0;
        for (int e = e0; e < e1; ++e) {
            int s = sNext;
            if (e + 1 < e1) sNext = srcarr[e + 1];  // prefetch index one ahead
            res += di * dinv[s] * sup[(size_t)s * 64 + lane];
        }
        h[(size_t)i * 64 + lane] = fmaxf(res, 0.0f);
    }
}

// ---------------- head: log_softmax(h @ W_out + b_out) ----------------
__global__ void k_out(const float* __restrict__ h, const float* __restrict__ Wout,
                      const float* __restrict__ bout, float* __restrict__ out, int N) {
    int lane = threadIdx.x & 63;
    int wave = (blockIdx.x * blockDim.x + threadIdx.x) >> 6;
    int nwaves = (gridDim.x * blockDim.x) >> 6;
    float w0 = Wout[lane * 2 + 0], w1 = Wout[lane * 2 + 1];
    float b0 = bout[0], b1 = bout[1];
    for (int i = wave; i < N; i += nwaves) {
        float hv = h[(size_t)i * 64 + lane];
        float p0 = hv * w0, p1 = hv * w1;
#pragma unroll
        for (int d = 32; d > 0; d >>= 1) {
            p0 += __shfl_xor(p0, d, 64);
            p1 += __shfl_xor(p1, d, 64);
        }
        if (lane == 0) {
            float c0 = p0 + b0, c1 = p1 + b1;
            float m = fmaxf(c0, c1);
            float lse = m + logf(expf(c0 - m) + expf(c1 - m));
            out[(size_t)i * 2 + 0] = c0 - lse;
            out[(size_t)i * 2 + 1] = c1 - lse;
        }
    }
}

extern "C" void kernel_launch(void* const* d_in, const int* in_sizes, int n_in,
                              void* d_out, int out_size, void* d_ws, size_t ws_size,
                              hipStream_t stream) {
    const float* x    = (const float*)d_in[0];
    const int*   ei   = (const int*)d_in[1];   // int32 (jax default x64-disabled)
    const float* Win  = (const float*)d_in[2];
    const float* bin  = (const float*)d_in[3];
    const float* W1   = (const float*)d_in[4];
    const float* W2   = (const float*)d_in[5];
    const float* Wout = (const float*)d_in[6];
    const float* bout = (const float*)d_in[7];
    float* out = (float*)d_out;

    const int N = in_sizes[0] / 17;
    const int E = in_sizes[1] / 2;
    const int* rowp = ei;
    const int* colp = ei + E;

    // workspace layout (256B aligned slices)
    char* p = (char*)d_ws;
    auto alloc = [&](size_t bytes) -> char* {
        char* r = p;
        p += (bytes + 255) & ~(size_t)255;
        return r;
    };
    int*   offs   = (int*)alloc((size_t)(N + 1) * sizeof(int));
    int*   count  = (int*)alloc((size_t)N * sizeof(int));
    int*   cursor = (int*)alloc((size_t)N * sizeof(int));
    float* dinv   = (float*)alloc((size_t)N * sizeof(float));
    int*   bsum   = (int*)alloc(1024 * sizeof(int));
    int*   srcarr = (int*)alloc((size_t)E * sizeof(int));
    float* h0     = (float*)alloc((size_t)N * 64 * sizeof(float));
    float* h      = (float*)alloc((size_t)N * 64 * sizeof(float));
    float* sup    = (float*)alloc((size_t)N * 64 * sizeof(float));

    hipMemsetAsync(count, 0, (size_t)N * sizeof(int), stream);
    hipMemsetAsync(cursor, 0, (size_t)N * sizeof(int), stream);

    const int TB = 256;
    const int nbN = (N + TB - 1) / TB;   // 391
    const int nbE = (E + TB - 1) / TB;

    k_hist<<<nbE, TB, 0, stream>>>(colp, E, count);
    k_dinv<<<nbN, TB, 0, stream>>>(count, dinv, N);
    k_scan1<<<nbN, TB, 0, stream>>>(count, N, offs, bsum);
    k_scan2<<<1, 512, 0, stream>>>(bsum, nbN);
    k_scan3<<<nbN, TB, 0, stream>>>(offs, bsum, N, E);
    k_scatter<<<nbE, TB, 0, stream>>>(rowp, colp, offs, cursor, srcarr, E);

    k_in<<<2048, 256, 0, stream>>>(x, Win, bin, h0, N);

    const float* hin = h0;
    for (int l = 0; l < 4; ++l) {
        float beta = logf(0.5f / (float)(l + 1) + 1.0f);
        k_support<<<2048, 256, 0, stream>>>(hin, W1 + (size_t)l * 4096, beta, sup, N);
        k_agg<<<2048, 256, 0, stream>>>(sup, h0, W2 + (size_t)l * 4096, dinv,
                                        offs, srcarr, beta, h, N);
        hin = h;
    }
    k_out<<<1024, 256, 0, stream>>>(h, Wout, bout, out, N);
}

// Round 2
// 995.021 us; speedup vs baseline: 1.0659x; 1.0659x over previous
//
#include <hip/hip_runtime.h>
#include <math.h>

#define ALPHA_C 0.1f

__device__ __forceinline__ float readlane_f(float v, int l) {
    return __int_as_float(__builtin_amdgcn_readlane(__float_as_int(v), l));
}

// ---------------- CSR build ----------------
__global__ void k_hist(const int* __restrict__ col, int E, int* __restrict__ count) {
    int i = blockIdx.x * blockDim.x + threadIdx.x;
    if (i < E) atomicAdd(&count[col[i]], 1);
}

__global__ void k_dinv(const int* __restrict__ count, float* __restrict__ dinv, int N) {
    int i = blockIdx.x * blockDim.x + threadIdx.x;
    if (i < N) dinv[i] = rsqrtf(1.0f + (float)count[i]);  // +1 = self loop
}

__global__ void k_scan1(const int* __restrict__ count, int N,
                        int* __restrict__ offs, int* __restrict__ bsum) {
    __shared__ int s[256];
    int tid = threadIdx.x;
    int gid = blockIdx.x * 256 + tid;
    int v = (gid < N) ? count[gid] : 0;
    s[tid] = v;
    __syncthreads();
    for (int d = 1; d < 256; d <<= 1) {
        int t = (tid >= d) ? s[tid - d] : 0;
        __syncthreads();
        s[tid] += t;
        __syncthreads();
    }
    if (gid < N) offs[gid] = s[tid] - v;      // block-local exclusive
    if (tid == 255) bsum[blockIdx.x] = s[255];
}

__global__ void k_scan2(int* __restrict__ bsum, int B) {
    __shared__ int s[512];
    int tid = threadIdx.x;
    int v = (tid < B) ? bsum[tid] : 0;
    s[tid] = v;
    __syncthreads();
    for (int d = 1; d < 512; d <<= 1) {
        int t = (tid >= d) ? s[tid - d] : 0;
        __syncthreads();
        s[tid] += t;
        __syncthreads();
    }
    if (tid < B) bsum[tid] = s[tid] - v;      // exclusive block bases
}

__global__ void k_scan3(int* __restrict__ offs, const int* __restrict__ bsum, int N, int E) {
    int gid = blockIdx.x * blockDim.x + threadIdx.x;
    if (gid < N) offs[gid] += bsum[blockIdx.x];
    if (gid == 0) offs[N] = E;
}

__global__ void k_scatter(const int* __restrict__ row, const int* __restrict__ col,
                          const int* __restrict__ offs, int* __restrict__ cursor,
                          int* __restrict__ srcarr, int E) {
    int e = blockIdx.x * blockDim.x + threadIdx.x;
    if (e < E) {
        int c = col[e];
        int pos = offs[c] + atomicAdd(&cursor[c], 1);
        srcarr[pos] = row[e];
    }
}

// ------- input transform: h0 = relu(x @ W_in + b_in);  g = dinv * h0 -------
__global__ void k_in(const float* __restrict__ x, const float* __restrict__ Win,
                     const float* __restrict__ bin, const float* __restrict__ dinv,
                     float* __restrict__ h0, float* __restrict__ g, int N) {
    int lane = threadIdx.x & 63;
    int wave = (blockIdx.x * blockDim.x + threadIdx.x) >> 6;
    int nwaves = (gridDim.x * blockDim.x) >> 6;
    float wreg[17];
#pragma unroll
    for (int k = 0; k < 17; ++k) wreg[k] = Win[k * 64 + lane];
    float breg = bin[lane];
    for (int i = wave; i < N; i += nwaves) {
        float xv = (lane < 17) ? x[i * 17 + lane] : 0.0f;
        float acc = breg;
#pragma unroll
        for (int k = 0; k < 17; ++k) acc += readlane_f(xv, k) * wreg[k];
        float r = fmaxf(acc, 0.0f);
        h0[(size_t)i * 64 + lane] = r;
        g[(size_t)i * 64 + lane] = dinv[i] * r;
    }
}

// ---- gather: A[i] = dinv[i] * ( sum_{e in CSR(i)} g[src] + g[i] ) ----
// g is pre-scaled by dinv, so per-edge work = one row load + add. 8-deep MLP.
__global__ void k_gather(const float* __restrict__ g, const float* __restrict__ dinv,
                         const int* __restrict__ offs, const int* __restrict__ srcarr,
                         float* __restrict__ A, int N) {
    int lane = threadIdx.x & 63;
    int wave = (blockIdx.x * blockDim.x + threadIdx.x) >> 6;
    int nwaves = (gridDim.x * blockDim.x) >> 6;
    for (int i = wave; i < N; i += nwaves) {
        int e0 = offs[i], e1 = offs[i + 1];
        float di = dinv[i];
        float gi = g[(size_t)i * 64 + lane];
        float acc[8];
#pragma unroll
        for (int u = 0; u < 8; ++u) acc[u] = 0.0f;
        for (int base = e0; base < e1; base += 8) {
            int idx[8];
#pragma unroll
            for (int u = 0; u < 8; ++u) {
                int ee = base + u;
                idx[u] = srcarr[ee < e1 ? ee : e1 - 1];  // tail: clamp to a hot row
            }
            float v[8];
#pragma unroll
            for (int u = 0; u < 8; ++u) v[u] = g[(size_t)idx[u] * 64 + lane];
#pragma unroll
            for (int u = 0; u < 8; ++u) acc[u] += (base + u < e1) ? v[u] : 0.0f;
        }
        float s01 = (acc[0] + acc[1]) + (acc[2] + acc[3]);
        float s23 = (acc[4] + acc[5]) + (acc[6] + acc[7]);
        A[(size_t)i * 64 + lane] = di * ((s01 + s23) + gi);
    }
}

// ---- mix: h_new = relu( A @ (beta*W1 + c1*I) + h0 @ (beta*W2 + c2*I) ) ----
// (support-transform commutes with the linear scatter, so it's applied once
//  per destination here instead of per-source before the gather)
template <bool WRITE_G>
__global__ void k_mix(const float* __restrict__ A, const float* __restrict__ h0,
                      const float* __restrict__ W1, const float* __restrict__ W2,
                      const float* __restrict__ dinv, float beta,
                      float* __restrict__ outbuf, int N) {
    int lane = threadIdx.x & 63;
    int wave = (blockIdx.x * blockDim.x + threadIdx.x) >> 6;
    int nwaves = (gridDim.x * blockDim.x) >> 6;
    float c1 = (1.0f - beta) * (1.0f - ALPHA_C);
    float c2 = (1.0f - beta) * ALPHA_C;
    float w1r[64], w2r[64];  // columns of the folded weights, in VGPRs
#pragma unroll
    for (int k = 0; k < 64; ++k) {
        w1r[k] = beta * W1[k * 64 + lane] + ((k == lane) ? c1 : 0.0f);
        w2r[k] = beta * W2[k * 64 + lane] + ((k == lane) ? c2 : 0.0f);
    }
    int i = wave;
    if (i >= N) return;
    float av = A[(size_t)i * 64 + lane];
    float hv = h0[(size_t)i * 64 + lane];
    while (i < N) {
        int inext = i + nwaves;
        float avn = 0.0f, hvn = 0.0f;
        if (inext < N) {  // prefetch next node while this one computes
            avn = A[(size_t)inext * 64 + lane];
            hvn = h0[(size_t)inext * 64 + lane];
        }
        float acc = 0.0f;
#pragma unroll
        for (int k = 0; k < 64; ++k) acc += readlane_f(av, k) * w1r[k];
#pragma unroll
        for (int k = 0; k < 64; ++k) acc += readlane_f(hv, k) * w2r[k];
        float r = fmaxf(acc, 0.0f);
        if (WRITE_G) outbuf[(size_t)i * 64 + lane] = dinv[i] * r;  // g for next gather
        else         outbuf[(size_t)i * 64 + lane] = r;            // final h
        i = inext; av = avn; hv = hvn;
    }
}

// ---------------- head: log_softmax(h @ W_out + b_out) ----------------
__global__ void k_out(const float* __restrict__ h, const float* __restrict__ Wout,
                      const float* __restrict__ bout, float* __restrict__ out, int N) {
    int lane = threadIdx.x & 63;
    int wave = (blockIdx.x * blockDim.x + threadIdx.x) >> 6;
    int nwaves = (gridDim.x * blockDim.x) >> 6;
    float w0 = Wout[lane * 2 + 0], w1 = Wout[lane * 2 + 1];
    float b0 = bout[0], b1 = bout[1];
    for (int i = wave; i < N; i += nwaves) {
        float hv = h[(size_t)i * 64 + lane];
        float p0 = hv * w0, p1 = hv * w1;
#pragma unroll
        for (int d = 32; d > 0; d >>= 1) {
            p0 += __shfl_xor(p0, d, 64);
            p1 += __shfl_xor(p1, d, 64);
        }
        if (lane == 0) {
            float c0 = p0 + b0, c1 = p1 + b1;
            float m = fmaxf(c0, c1);
            float lse = m + logf(expf(c0 - m) + expf(c1 - m));
            out[(size_t)i * 2 + 0] = c0 - lse;
            out[(size_t)i * 2 + 1] = c1 - lse;
        }
    }
}

extern "C" void kernel_launch(void* const* d_in, const int* in_sizes, int n_in,
                              void* d_out, int out_size, void* d_ws, size_t ws_size,
                              hipStream_t stream) {
    const float* x    = (const float*)d_in[0];
    const int*   ei   = (const int*)d_in[1];
    const float* Win  = (const float*)d_in[2];
    const float* bin  = (const float*)d_in[3];
    const float* W1   = (const float*)d_in[4];
    const float* W2   = (const float*)d_in[5];
    const float* Wout = (const float*)d_in[6];
    const float* bout = (const float*)d_in[7];
    float* out = (float*)d_out;

    const int N = in_sizes[0] / 17;
    const int E = in_sizes[1] / 2;
    const int* rowp = ei;
    const int* colp = ei + E;

    char* p = (char*)d_ws;
    auto alloc = [&](size_t bytes) -> char* {
        char* r = p;
        p += (bytes + 255) & ~(size_t)255;
        return r;
    };
    int*   offs   = (int*)alloc((size_t)(N + 1) * sizeof(int));
    int*   count  = (int*)alloc((size_t)N * sizeof(int));
    int*   cursor = (int*)alloc((size_t)N * sizeof(int));
    float* dinv   = (float*)alloc((size_t)N * sizeof(float));
    int*   bsum   = (int*)alloc(1024 * sizeof(int));
    int*   srcarr = (int*)alloc((size_t)E * sizeof(int));
    float* h0     = (float*)alloc((size_t)N * 64 * sizeof(float));
    float* B1     = (float*)alloc((size_t)N * 64 * sizeof(float));  // g / final h
    float* B2     = (float*)alloc((size_t)N * 64 * sizeof(float));  // A

    hipMemsetAsync(count, 0, (size_t)N * sizeof(int), stream);
    hipMemsetAsync(cursor, 0, (size_t)N * sizeof(int), stream);

    const int TB = 256;
    const int nbN = (N + TB - 1) / TB;
    const int nbE = (E + TB - 1) / TB;

    k_hist<<<nbE, TB, 0, stream>>>(colp, E, count);
    k_dinv<<<nbN, TB, 0, stream>>>(count, dinv, N);
    k_scan1<<<nbN, TB, 0, stream>>>(count, N, offs, bsum);
    k_scan2<<<1, 512, 0, stream>>>(bsum, nbN);
    k_scan3<<<nbN, TB, 0, stream>>>(offs, bsum, N, E);
    k_scatter<<<nbE, TB, 0, stream>>>(rowp, colp, offs, cursor, srcarr, E);

    k_in<<<2048, 256, 0, stream>>>(x, Win, bin, dinv, h0, B1, N);

    for (int l = 0; l < 4; ++l) {
        float beta = logf(0.5f / (float)(l + 1) + 1.0f);
        k_gather<<<2048, 256, 0, stream>>>(B1, dinv, offs, srcarr, B2, N);
        if (l < 3)
            k_mix<true><<<2048, 256, 0, stream>>>(B2, h0, W1 + (size_t)l * 4096,
                                                  W2 + (size_t)l * 4096, dinv, beta, B1, N);
        else
            k_mix<false><<<2048, 256, 0, stream>>>(B2, h0, W1 + (size_t)l * 4096,
                                                   W2 + (size_t)l * 4096, dinv, beta, B1, N);
    }
    k_out<<<1024, 256, 0, stream>>>(B1, Wout, bout, out, N);
}

// Round 3
// 567.859 us; speedup vs baseline: 1.8677x; 1.7522x over previous
//
#include <hip/hip_runtime.h>
#include <math.h>

#define ALPHA_C 0.1f

typedef __attribute__((ext_vector_type(4))) float f32x4;
typedef __attribute__((ext_vector_type(8))) short bf16x8;

__device__ __forceinline__ float readlane_f(float v, int l) {
    return __int_as_float(__builtin_amdgcn_readlane(__float_as_int(v), l));
}

__device__ __forceinline__ short bf16_rtne(float f) {
    unsigned u = __float_as_uint(f);
    unsigned r = (u + 0x7FFFu + ((u >> 16) & 1u)) >> 16;
    return (short)r;
}

// ---------------- CSR build ----------------
__global__ void k_hist(const int* __restrict__ col, int E, int* __restrict__ count) {
    int i = blockIdx.x * blockDim.x + threadIdx.x;
    if (i < E) atomicAdd(&count[col[i]], 1);
}

__global__ void k_dinv(const int* __restrict__ count, float* __restrict__ dinv, int N) {
    int i = blockIdx.x * blockDim.x + threadIdx.x;
    if (i < N) dinv[i] = rsqrtf(1.0f + (float)count[i]);  // +1 = self loop
}

__global__ void k_scan1(const int* __restrict__ count, int N,
                        int* __restrict__ offs, int* __restrict__ bsum) {
    __shared__ int s[256];
    int tid = threadIdx.x;
    int gid = blockIdx.x * 256 + tid;
    int v = (gid < N) ? count[gid] : 0;
    s[tid] = v;
    __syncthreads();
    for (int d = 1; d < 256; d <<= 1) {
        int t = (tid >= d) ? s[tid - d] : 0;
        __syncthreads();
        s[tid] += t;
        __syncthreads();
    }
    if (gid < N) offs[gid] = s[tid] - v;      // block-local exclusive
    if (tid == 255) bsum[blockIdx.x] = s[255];
}

__global__ void k_scan2(int* __restrict__ bsum, int B) {
    __shared__ int s[512];
    int tid = threadIdx.x;
    int v = (tid < B) ? bsum[tid] : 0;
    s[tid] = v;
    __syncthreads();
    for (int d = 1; d < 512; d <<= 1) {
        int t = (tid >= d) ? s[tid - d] : 0;
        __syncthreads();
        s[tid] += t;
        __syncthreads();
    }
    if (tid < B) bsum[tid] = s[tid] - v;      // exclusive block bases
}

__global__ void k_scan3(int* __restrict__ offs, const int* __restrict__ bsum, int N, int E) {
    int gid = blockIdx.x * blockDim.x + threadIdx.x;
    if (gid < N) offs[gid] += bsum[blockIdx.x];
    if (gid == 0) offs[N] = E;
}

__global__ void k_scatter(const int* __restrict__ row, const int* __restrict__ col,
                          const int* __restrict__ offs, int* __restrict__ cursor,
                          int* __restrict__ srcarr, int E) {
    int e = blockIdx.x * blockDim.x + threadIdx.x;
    if (e < E) {
        int c = col[e];
        int pos = offs[c] + atomicAdd(&cursor[c], 1);
        srcarr[pos] = row[e];
    }
}

// ------- input transform: h0 = relu(x @ W_in + b_in);  g = dinv * h0 -------
__global__ void k_in(const float* __restrict__ x, const float* __restrict__ Win,
                     const float* __restrict__ bin, const float* __restrict__ dinv,
                     float* __restrict__ h0, float* __restrict__ g, int N) {
    int lane = threadIdx.x & 63;
    int wave = (blockIdx.x * blockDim.x + threadIdx.x) >> 6;
    int nwaves = (gridDim.x * blockDim.x) >> 6;
    float wreg[17];
#pragma unroll
    for (int k = 0; k < 17; ++k) wreg[k] = Win[k * 64 + lane];
    float breg = bin[lane];
    for (int i = wave; i < N; i += nwaves) {
        float xv = (lane < 17) ? x[i * 17 + lane] : 0.0f;
        float acc = breg;
#pragma unroll
        for (int k = 0; k < 17; ++k) acc += readlane_f(xv, k) * wreg[k];
        float r = fmaxf(acc, 0.0f);
        h0[(size_t)i * 64 + lane] = r;
        g[(size_t)i * 64 + lane] = dinv[i] * r;
    }
}

// ---- gather: A[i] = dinv[i] * ( sum_{e in CSR(i)} g[src] + g[i] ) ----
__global__ void k_gather(const float* __restrict__ g, const float* __restrict__ dinv,
                         const int* __restrict__ offs, const int* __restrict__ srcarr,
                         float* __restrict__ A, int N) {
    int lane = threadIdx.x & 63;
    int wave = (blockIdx.x * blockDim.x + threadIdx.x) >> 6;
    int nwaves = (gridDim.x * blockDim.x) >> 6;
    for (int i = wave; i < N; i += nwaves) {
        int e0 = offs[i], e1 = offs[i + 1];
        float di = dinv[i];
        float gi = g[(size_t)i * 64 + lane];
        float acc[8];
#pragma unroll
        for (int u = 0; u < 8; ++u) acc[u] = 0.0f;
        for (int base = e0; base < e1; base += 8) {
            int idx[8];
#pragma unroll
            for (int u = 0; u < 8; ++u) {
                int ee = base + u;
                idx[u] = srcarr[ee < e1 ? ee : e1 - 1];  // tail: clamp to a hot row
            }
            float v[8];
#pragma unroll
            for (int u = 0; u < 8; ++u) v[u] = g[(size_t)idx[u] * 64 + lane];
#pragma unroll
            for (int u = 0; u < 8; ++u) acc[u] += (base + u < e1) ? v[u] : 0.0f;
        }
        float s01 = (acc[0] + acc[1]) + (acc[2] + acc[3]);
        float s23 = (acc[4] + acc[5]) + (acc[6] + acc[7]);
        A[(size_t)i * 64 + lane] = di * ((s01 + s23) + gi);
    }
}

// ---- mix (MFMA): out = relu( c1*A + c2*h0 + bf16mfma([A|h0] @ [bW1;bW2]) ) ----
// Identity/residual path stays f32; only the beta-scaled W-products go through
// bf16 MFMA (beta in [0.12,0.41], W ~ N(0,0.01) -> error well under threshold).
// mfma_f32_16x16x32_bf16 layouts: A/B frag lane l: m|n = l&15, k = (l>>4)*8+j;
// C/D: col = l&15, row = (l>>4)*4 + q   [m89-verified]
template <bool WRITE_G>
__global__ void k_mix(const float* __restrict__ Abuf, const float* __restrict__ h0,
                      const float* __restrict__ W1, const float* __restrict__ W2,
                      const float* __restrict__ dinv, float beta,
                      float* __restrict__ obuf, int N) {
    int lane = threadIdx.x & 63;
    int wid = (blockIdx.x * blockDim.x + threadIdx.x) >> 6;
    int nw = (gridDim.x * blockDim.x) >> 6;
    float c1 = (1.0f - beta) * (1.0f - ALPHA_C);
    float c2 = (1.0f - beta) * ALPHA_C;

    // B fragments: folded beta*W, built once per wave, resident in VGPRs.
    bf16x8 bfrag[4][4];  // [col-tile c][k-step ks]
#pragma unroll
    for (int c = 0; c < 4; ++c) {
#pragma unroll
        for (int ks = 0; ks < 4; ++ks) {
            int n = c * 16 + (lane & 15);
            int kb = ks * 32 + (lane >> 4) * 8;
            bf16x8 f;
#pragma unroll
            for (int j = 0; j < 8; ++j) {
                int k = kb + j;
                float w = (k < 64) ? beta * W1[k * 64 + n]
                                   : beta * W2[(k - 64) * 64 + n];
                f[j] = bf16_rtne(w);
            }
            bfrag[c][ks] = f;
        }
    }

    int ntiles = (N + 15) >> 4;
    for (int t = wid; t < ntiles; t += nw) {
        // ---- A fragments: rows from Abuf (ks 0,1) and h0 (ks 2,3) ----
        int arow = t * 16 + (lane & 15);
        if (arow >= N) arow = N - 1;
        int koff = (lane >> 4) * 8;
        f32x4 acc[4];
#pragma unroll
        for (int c = 0; c < 4; ++c) acc[c] = (f32x4){0.f, 0.f, 0.f, 0.f};
#pragma unroll
        for (int ks = 0; ks < 4; ++ks) {
            const float* sp = (ks < 2)
                ? &Abuf[(size_t)arow * 64 + ks * 32 + koff]
                : &h0[(size_t)arow * 64 + (ks - 2) * 32 + koff];
            f32x4 lo = *(const f32x4*)sp;
            f32x4 hi = *(const f32x4*)(sp + 4);
            bf16x8 af;
#pragma unroll
            for (int j = 0; j < 4; ++j) af[j] = bf16_rtne(lo[j]);
#pragma unroll
            for (int j = 0; j < 4; ++j) af[4 + j] = bf16_rtne(hi[j]);
#pragma unroll
            for (int c = 0; c < 4; ++c)
                acc[c] = __builtin_amdgcn_mfma_f32_16x16x32_bf16(af, bfrag[c][ks], acc[c], 0, 0, 0);
        }
        // ---- epilogue: f32 residual + relu (+ dinv prescale for next gather) ----
#pragma unroll
        for (int c = 0; c < 4; ++c) {
            int col = c * 16 + (lane & 15);
#pragma unroll
            for (int q = 0; q < 4; ++q) {
                int row = t * 16 + (lane >> 4) * 4 + q;
                if (row < N) {
                    size_t o = (size_t)row * 64 + col;
                    float v = c1 * Abuf[o] + c2 * h0[o] + acc[c][q];
                    float r = fmaxf(v, 0.0f);
                    obuf[o] = WRITE_G ? dinv[row] * r : r;
                }
            }
        }
    }
}

// ---------------- head: log_softmax(h @ W_out + b_out) ----------------
__global__ void k_out(const float* __restrict__ h, const float* __restrict__ Wout,
                      const float* __restrict__ bout, float* __restrict__ out, int N) {
    int lane = threadIdx.x & 63;
    int wave = (blockIdx.x * blockDim.x + threadIdx.x) >> 6;
    int nwaves = (gridDim.x * blockDim.x) >> 6;
    float w0 = Wout[lane * 2 + 0], w1 = Wout[lane * 2 + 1];
    float b0 = bout[0], b1 = bout[1];
    for (int i = wave; i < N; i += nwaves) {
        float hv = h[(size_t)i * 64 + lane];
        float p0 = hv * w0, p1 = hv * w1;
#pragma unroll
        for (int d = 32; d > 0; d >>= 1) {
            p0 += __shfl_xor(p0, d, 64);
            p1 += __shfl_xor(p1, d, 64);
        }
        if (lane == 0) {
            float c0 = p0 + b0, c1 = p1 + b1;
            float m = fmaxf(c0, c1);
            float lse = m + logf(expf(c0 - m) + expf(c1 - m));
            out[(size_t)i * 2 + 0] = c0 - lse;
            out[(size_t)i * 2 + 1] = c1 - lse;
        }
    }
}

extern "C" void kernel_launch(void* const* d_in, const int* in_sizes, int n_in,
                              void* d_out, int out_size, void* d_ws, size_t ws_size,
                              hipStream_t stream) {
    const float* x    = (const float*)d_in[0];
    const int*   ei   = (const int*)d_in[1];
    const float* Win  = (const float*)d_in[2];
    const float* bin  = (const float*)d_in[3];
    const float* W1   = (const float*)d_in[4];
    const float* W2   = (const float*)d_in[5];
    const float* Wout = (const float*)d_in[6];
    const float* bout = (const float*)d_in[7];
    float* out = (float*)d_out;

    const int N = in_sizes[0] / 17;
    const int E = in_sizes[1] / 2;
    const int* rowp = ei;
    const int* colp = ei + E;

    char* p = (char*)d_ws;
    auto alloc = [&](size_t bytes) -> char* {
        char* r = p;
        p += (bytes + 255) & ~(size_t)255;
        return r;
    };
    int*   offs   = (int*)alloc((size_t)(N + 1) * sizeof(int));
    int*   count  = (int*)alloc((size_t)N * sizeof(int));
    int*   cursor = (int*)alloc((size_t)N * sizeof(int));
    float* dinv   = (float*)alloc((size_t)N * sizeof(float));
    int*   bsum   = (int*)alloc(1024 * sizeof(int));
    int*   srcarr = (int*)alloc((size_t)E * sizeof(int));
    float* h0     = (float*)alloc((size_t)N * 64 * sizeof(float));
    float* B1     = (float*)alloc((size_t)N * 64 * sizeof(float));  // g / final h
    float* B2     = (float*)alloc((size_t)N * 64 * sizeof(float));  // A

    hipMemsetAsync(count, 0, (size_t)N * sizeof(int), stream);
    hipMemsetAsync(cursor, 0, (size_t)N * sizeof(int), stream);

    const int TB = 256;
    const int nbN = (N + TB - 1) / TB;
    const int nbE = (E + TB - 1) / TB;

    k_hist<<<nbE, TB, 0, stream>>>(colp, E, count);
    k_dinv<<<nbN, TB, 0, stream>>>(count, dinv, N);
    k_scan1<<<nbN, TB, 0, stream>>>(count, N, offs, bsum);
    k_scan2<<<1, 512, 0, stream>>>(bsum, nbN);
    k_scan3<<<nbN, TB, 0, stream>>>(offs, bsum, N, E);
    k_scatter<<<nbE, TB, 0, stream>>>(rowp, colp, offs, cursor, srcarr, E);

    k_in<<<2048, 256, 0, stream>>>(x, Win, bin, dinv, h0, B1, N);

    for (int l = 0; l < 4; ++l) {
        float beta = logf(0.5f / (float)(l + 1) + 1.0f);
        k_gather<<<2048, 256, 0, stream>>>(B1, dinv, offs, srcarr, B2, N);
        if (l < 3)
            k_mix<true><<<512, 256, 0, stream>>>(B2, h0, W1 + (size_t)l * 4096,
                                                 W2 + (size_t)l * 4096, dinv, beta, B1, N);
        else
            k_mix<false><<<512, 256, 0, stream>>>(B2, h0, W1 + (size_t)l * 4096,
                                                  W2 + (size_t)l * 4096, dinv, beta, B1, N);
    }
    k_out<<<1024, 256, 0, stream>>>(B1, Wout, bout, out, N);
}

// Round 4
// 488.428 us; speedup vs baseline: 2.1714x; 1.1626x over previous
//
#include <hip/hip_runtime.h>
#include <math.h>

#define ALPHA_C 0.1f

typedef __attribute__((ext_vector_type(4))) float f32x4;
typedef __attribute__((ext_vector_type(2))) float f32x2;
typedef __attribute__((ext_vector_type(8))) short bf16x8;

__device__ __forceinline__ float readlane_f(float v, int l) {
    return __int_as_float(__builtin_amdgcn_readlane(__float_as_int(v), l));
}

__device__ __forceinline__ unsigned short bf16_rtne(float f) {
    unsigned u = __float_as_uint(f);
    unsigned r = (u + 0x7FFFu + ((u >> 16) & 1u)) >> 16;
    return (unsigned short)r;
}

// ---------------- CSR build ----------------
__global__ void k_hist(const int* __restrict__ col, int E, int* __restrict__ count) {
    int i = blockIdx.x * blockDim.x + threadIdx.x;
    if (i < E) atomicAdd(&count[col[i]], 1);
}

__global__ void k_dinv(const int* __restrict__ count, float* __restrict__ dinv, int N) {
    int i = blockIdx.x * blockDim.x + threadIdx.x;
    if (i < N) dinv[i] = rsqrtf(1.0f + (float)count[i]);  // +1 = self loop
}

__global__ void k_scan1(const int* __restrict__ count, int N,
                        int* __restrict__ offs, int* __restrict__ bsum) {
    __shared__ int s[256];
    int tid = threadIdx.x;
    int gid = blockIdx.x * 256 + tid;
    int v = (gid < N) ? count[gid] : 0;
    s[tid] = v;
    __syncthreads();
    for (int d = 1; d < 256; d <<= 1) {
        int t = (tid >= d) ? s[tid - d] : 0;
        __syncthreads();
        s[tid] += t;
        __syncthreads();
    }
    if (gid < N) offs[gid] = s[tid] - v;
    if (tid == 255) bsum[blockIdx.x] = s[255];
}

__global__ void k_scan2(int* __restrict__ bsum, int B) {
    __shared__ int s[512];
    int tid = threadIdx.x;
    int v = (tid < B) ? bsum[tid] : 0;
    s[tid] = v;
    __syncthreads();
    for (int d = 1; d < 512; d <<= 1) {
        int t = (tid >= d) ? s[tid - d] : 0;
        __syncthreads();
        s[tid] += t;
        __syncthreads();
    }
    if (tid < B) bsum[tid] = s[tid] - v;
}

__global__ void k_scan3(int* __restrict__ offs, const int* __restrict__ bsum, int N, int E) {
    int gid = blockIdx.x * blockDim.x + threadIdx.x;
    if (gid < N) offs[gid] += bsum[blockIdx.x];
    if (gid == 0) offs[N] = E;
}

// ---- scatter phase A: bin edges into 64 destination ranges (write-amp ~1x) ----
// staged layout: range r occupies [offs[r*span], offs[min((r+1)*span,N)]) like the
// final CSR, but edges within a range are unordered. Per-block LDS histogram ->
// one global atomic per (block,range) -> contiguous ~64-entry runs.
#define EPB 4096  // edges per block (16 per thread)
__global__ void k_binA(const int* __restrict__ row, const int* __restrict__ col,
                       const int* __restrict__ offs, int* __restrict__ gcur,
                       uint2* __restrict__ staged, int E, int N, int span) {
    __shared__ int lrun[64];
    int tid = threadIdx.x;
    int base = blockIdx.x * EPB;
    if (tid < 64) lrun[tid] = 0;
    __syncthreads();
    // pass 1: local histogram
#pragma unroll
    for (int it = 0; it < 16; ++it) {
        int e = base + it * 256 + tid;
        if (e < E) atomicAdd(&lrun[(unsigned)col[e] / (unsigned)span], 1);
    }
    __syncthreads();
    if (tid < 64) {
        int cnt = lrun[tid];
        int nstart = tid * span; if (nstart > N) nstart = N;
        int gb = cnt ? atomicAdd(&gcur[tid], cnt) : 0;
        lrun[tid] = offs[nstart] + gb;  // absolute staged cursor for this block+range
    }
    __syncthreads();
    // pass 2: place
#pragma unroll
    for (int it = 0; it < 16; ++it) {
        int e = base + it * 256 + tid;
        if (e < E) {
            int c = col[e];
            int r = (unsigned)c / (unsigned)span;
            int pos = atomicAdd(&lrun[r], 1);
            staged[pos] = make_uint2((unsigned)c, (unsigned)row[e]);
        }
    }
}

// ---- scatter phase B: one block per range; LDS cursors; writes stay in one L2 ----
__global__ void k_binB(const uint2* __restrict__ staged, const int* __restrict__ offs,
                       int* __restrict__ srcarr, int N, int span) {
    __shared__ int lcur[1600];
    int r = blockIdx.x;
    int nstart = r * span;
    if (nstart >= N) return;
    int nend = nstart + span; if (nend > N) nend = N;
    int cnt = nend - nstart;
    for (int t = threadIdx.x; t < cnt; t += 256) lcur[t] = 0;
    __syncthreads();
    int estart = offs[nstart], eend = offs[nend];
    for (int e = estart + threadIdx.x; e < eend; e += 256) {
        uint2 cr = staged[e];
        int c = (int)cr.x;
        int idx = offs[c] + atomicAdd(&lcur[c - nstart], 1);
        srcarr[idx] = (int)cr.y;
    }
}

// ------- input: h0 = relu(x @ W_in + b_in);  g = bf16(dinv * h0) -------
__global__ void k_in(const float* __restrict__ x, const float* __restrict__ Win,
                     const float* __restrict__ bin, const float* __restrict__ dinv,
                     float* __restrict__ h0, unsigned short* __restrict__ g, int N) {
    int lane = threadIdx.x & 63;
    int wave = (blockIdx.x * blockDim.x + threadIdx.x) >> 6;
    int nwaves = (gridDim.x * blockDim.x) >> 6;
    float wreg[17];
#pragma unroll
    for (int k = 0; k < 17; ++k) wreg[k] = Win[k * 64 + lane];
    float breg = bin[lane];
    for (int i = wave; i < N; i += nwaves) {
        float xv = (lane < 17) ? x[i * 17 + lane] : 0.0f;
        float acc = breg;
#pragma unroll
        for (int k = 0; k < 17; ++k) acc += readlane_f(xv, k) * wreg[k];
        float r = fmaxf(acc, 0.0f);
        h0[(size_t)i * 64 + lane] = r;
        g[(size_t)i * 64 + lane] = bf16_rtne(dinv[i] * r);
    }
}

// ---- gather: A[i] = dinv[i]*(sum_e g[src] + g[i]); g is bf16 rows (128B) ----
// lane = (slot s = lane>>5, feature-pair p = lane&31). Each half-wave takes its
// own 8-edge batch -> 16 concurrent row loads per wave; f32 accumulate;
// cross-half combine with one shfl_xor(32).
__global__ void k_gather(const unsigned int* __restrict__ gp,  // g as uint (2 bf16)
                         const float* __restrict__ dinv,
                         const int* __restrict__ offs, const int* __restrict__ srcarr,
                         float* __restrict__ A, int N) {
    int lane = threadIdx.x & 63;
    int p = lane & 31;
    int s = lane >> 5;
    int wave = (blockIdx.x * blockDim.x + threadIdx.x) >> 6;
    int nwaves = (gridDim.x * blockDim.x) >> 6;
    for (int i = wave; i < N; i += nwaves) {
        int e0 = offs[i], e1 = offs[i + 1];
        float a0 = 0.0f, a1 = 0.0f;
        for (int base = e0 + s * 8; base < e1; base += 16) {
            int idx[8];
            unsigned v[8];
#pragma unroll
            for (int u = 0; u < 8; ++u) {
                int ee = base + u;
                idx[u] = srcarr[ee < e1 ? ee : e1 - 1];
            }
#pragma unroll
            for (int u = 0; u < 8; ++u) v[u] = gp[(size_t)idx[u] * 32 + p];
#pragma unroll
            for (int u = 0; u < 8; ++u) {
                bool ok = (base + u < e1);
                float lo = __uint_as_float(v[u] << 16);
                float hi = __uint_as_float(v[u] & 0xFFFF0000u);
                a0 += ok ? lo : 0.0f;
                a1 += ok ? hi : 0.0f;
            }
        }
        a0 += __shfl_xor(a0, 32, 64);
        a1 += __shfl_xor(a1, 32, 64);
        unsigned sv = gp[(size_t)i * 32 + p];  // self term (both halves compute)
        a0 += __uint_as_float(sv << 16);
        a1 += __uint_as_float(sv & 0xFFFF0000u);
        if (s == 0) {
            float di = dinv[i];
            f32x2 w = {di * a0, di * a1};
            *(f32x2*)&A[(size_t)i * 64 + 2 * p] = w;
        }
    }
}

// ---- mix (MFMA): out = relu( c1*A + c2*h0 + bf16mfma([A|h0] @ [bW1;bW2]) ) ----
// WRITE_G: out -> bf16 g (prescaled by dinv) for the next gather.
// else:    out -> f32 h, in place over A (safe: tile rows are wave-private).
template <bool WRITE_G>
__global__ void k_mix(const float* __restrict__ Abuf, const float* __restrict__ h0,
                      const float* __restrict__ W1, const float* __restrict__ W2,
                      const float* __restrict__ dinv, float beta,
                      float* __restrict__ of32, unsigned short* __restrict__ og16,
                      int N) {
    int lane = threadIdx.x & 63;
    int wid = (blockIdx.x * blockDim.x + threadIdx.x) >> 6;
    int nw = (gridDim.x * blockDim.x) >> 6;
    float c1 = (1.0f - beta) * (1.0f - ALPHA_C);
    float c2 = (1.0f - beta) * ALPHA_C;

    bf16x8 bfrag[4][4];  // [col-tile][k-step], folded beta*W
#pragma unroll
    for (int c = 0; c < 4; ++c) {
#pragma unroll
        for (int ks = 0; ks < 4; ++ks) {
            int n = c * 16 + (lane & 15);
            int kb = ks * 32 + (lane >> 4) * 8;
            bf16x8 f;
#pragma unroll
            for (int j = 0; j < 8; ++j) {
                int k = kb + j;
                float w = (k < 64) ? beta * W1[k * 64 + n]
                                   : beta * W2[(k - 64) * 64 + n];
                f[j] = (short)bf16_rtne(w);
            }
            bfrag[c][ks] = f;
        }
    }

    int ntiles = (N + 15) >> 4;
    for (int t = wid; t < ntiles; t += nw) {
        int arow = t * 16 + (lane & 15);
        if (arow >= N) arow = N - 1;
        int koff = (lane >> 4) * 8;
        f32x4 acc[4];
#pragma unroll
        for (int c = 0; c < 4; ++c) acc[c] = (f32x4){0.f, 0.f, 0.f, 0.f};
#pragma unroll
        for (int ks = 0; ks < 4; ++ks) {
            const float* sp = (ks < 2)
                ? &Abuf[(size_t)arow * 64 + ks * 32 + koff]
                : &h0[(size_t)arow * 64 + (ks - 2) * 32 + koff];
            f32x4 lo = *(const f32x4*)sp;
            f32x4 hi = *(const f32x4*)(sp + 4);
            bf16x8 af;
#pragma unroll
            for (int j = 0; j < 4; ++j) af[j] = (short)bf16_rtne(lo[j]);
#pragma unroll
            for (int j = 0; j < 4; ++j) af[4 + j] = (short)bf16_rtne(hi[j]);
#pragma unroll
            for (int c = 0; c < 4; ++c)
                acc[c] = __builtin_amdgcn_mfma_f32_16x16x32_bf16(af, bfrag[c][ks], acc[c], 0, 0, 0);
        }
#pragma unroll
        for (int c = 0; c < 4; ++c) {
            int col = c * 16 + (lane & 15);
#pragma unroll
            for (int q = 0; q < 4; ++q) {
                int row = t * 16 + (lane >> 4) * 4 + q;
                if (row < N) {
                    size_t o = (size_t)row * 64 + col;
                    float v = c1 * Abuf[o] + c2 * h0[o] + acc[c][q];
                    float r = fmaxf(v, 0.0f);
                    if (WRITE_G) og16[o] = bf16_rtne(dinv[row] * r);
                    else         of32[o] = r;
                }
            }
        }
    }
}

// ---------------- head: log_softmax(h @ W_out + b_out) ----------------
__global__ void k_out(const float* __restrict__ h, const float* __restrict__ Wout,
                      const float* __restrict__ bout, float* __restrict__ out, int N) {
    int lane = threadIdx.x & 63;
    int wave = (blockIdx.x * blockDim.x + threadIdx.x) >> 6;
    int nwaves = (gridDim.x * blockDim.x) >> 6;
    float w0 = Wout[lane * 2 + 0], w1 = Wout[lane * 2 + 1];
    float b0 = bout[0], b1 = bout[1];
    for (int i = wave; i < N; i += nwaves) {
        float hv = h[(size_t)i * 64 + lane];
        float p0 = hv * w0, p1 = hv * w1;
#pragma unroll
        for (int d = 32; d > 0; d >>= 1) {
            p0 += __shfl_xor(p0, d, 64);
            p1 += __shfl_xor(p1, d, 64);
        }
        if (lane == 0) {
            float c0 = p0 + b0, c1 = p1 + b1;
            float m = fmaxf(c0, c1);
            float lse = m + logf(expf(c0 - m) + expf(c1 - m));
            out[(size_t)i * 2 + 0] = c0 - lse;
            out[(size_t)i * 2 + 1] = c1 - lse;
        }
    }
}

extern "C" void kernel_launch(void* const* d_in, const int* in_sizes, int n_in,
                              void* d_out, int out_size, void* d_ws, size_t ws_size,
                              hipStream_t stream) {
    const float* x    = (const float*)d_in[0];
    const int*   ei   = (const int*)d_in[1];
    const float* Win  = (const float*)d_in[2];
    const float* bin  = (const float*)d_in[3];
    const float* W1   = (const float*)d_in[4];
    const float* W2   = (const float*)d_in[5];
    const float* Wout = (const float*)d_in[6];
    const float* bout = (const float*)d_in[7];
    float* out = (float*)d_out;

    const int N = in_sizes[0] / 17;
    const int E = in_sizes[1] / 2;
    const int* rowp = ei;
    const int* colp = ei + E;
    const int span = (N + 63) / 64;

    char* p = (char*)d_ws;
    auto alloc = [&](size_t bytes) -> char* {
        char* r = p;
        p += (bytes + 255) & ~(size_t)255;
        return r;
    };
    int*            offs   = (int*)alloc((size_t)(N + 1) * sizeof(int));
    int*            count  = (int*)alloc((size_t)N * sizeof(int));
    float*          dinv   = (float*)alloc((size_t)N * sizeof(float));
    int*            bsum   = (int*)alloc(1024 * sizeof(int));
    int*            gcur   = (int*)alloc(256 * sizeof(int));
    int*            srcarr = (int*)alloc((size_t)E * sizeof(int));
    uint2*          staged = (uint2*)alloc((size_t)E * sizeof(uint2));
    float*          h0     = (float*)alloc((size_t)N * 64 * sizeof(float));
    float*          Abuf   = (float*)alloc((size_t)N * 64 * sizeof(float));  // A / final h
    unsigned short* gbuf   = (unsigned short*)alloc((size_t)N * 64 * sizeof(unsigned short));

    hipMemsetAsync(count, 0, (size_t)N * sizeof(int), stream);
    hipMemsetAsync(gcur, 0, 256 * sizeof(int), stream);

    const int TB = 256;
    const int nbN = (N + TB - 1) / TB;
    const int nbE = (E + TB - 1) / TB;
    const int nbA = (E + EPB - 1) / EPB;

    k_hist<<<nbE, TB, 0, stream>>>(colp, E, count);
    k_dinv<<<nbN, TB, 0, stream>>>(count, dinv, N);
    k_scan1<<<nbN, TB, 0, stream>>>(count, N, offs, bsum);
    k_scan2<<<1, 512, 0, stream>>>(bsum, nbN);
    k_scan3<<<nbN, TB, 0, stream>>>(offs, bsum, N, E);
    k_binA<<<nbA, TB, 0, stream>>>(rowp, colp, offs, gcur, staged, E, N, span);
    k_binB<<<64, TB, 0, stream>>>(staged, offs, srcarr, N, span);

    k_in<<<2048, TB, 0, stream>>>(x, Win, bin, dinv, h0, gbuf, N);

    for (int l = 0; l < 4; ++l) {
        float beta = logf(0.5f / (float)(l + 1) + 1.0f);
        k_gather<<<1536, TB, 0, stream>>>((const unsigned int*)gbuf, dinv, offs,
                                          srcarr, Abuf, N);
        if (l < 3)
            k_mix<true><<<512, TB, 0, stream>>>(Abuf, h0, W1 + (size_t)l * 4096,
                                                W2 + (size_t)l * 4096, dinv, beta,
                                                nullptr, gbuf, N);
        else
            k_mix<false><<<512, TB, 0, stream>>>(Abuf, h0, W1 + (size_t)l * 4096,
                                                 W2 + (size_t)l * 4096, dinv, beta,
                                                 Abuf, nullptr, N);
    }
    k_out<<<1024, TB, 0, stream>>>(Abuf, Wout, bout, out, N);
}

// Round 5
// 470.672 us; speedup vs baseline: 2.2534x; 1.0377x over previous
//
#include <hip/hip_runtime.h>
#include <math.h>

#define ALPHA_C 0.1f
#define EPB 4096  // edges per block in binning kernels (16 per thread)

typedef __attribute__((ext_vector_type(4))) float f32x4;
typedef __attribute__((ext_vector_type(8))) short bf16x8;

__device__ __forceinline__ float readlane_f(float v, int l) {
    return __int_as_float(__builtin_amdgcn_readlane(__float_as_int(v), l));
}

__device__ __forceinline__ unsigned short bf16_rtne(float f) {
    unsigned u = __float_as_uint(f);
    unsigned r = (u + 0x7FFFu + ((u >> 16) & 1u)) >> 16;
    return (unsigned short)r;
}

// ---- range histogram: 64 coarse bins (no 100k-wide random atomics) ----
__global__ void k_rhist(const int* __restrict__ col, int E, int span,
                        int* __restrict__ rangecount) {
    __shared__ int l[64];
    int tid = threadIdx.x;
    if (tid < 64) l[tid] = 0;
    __syncthreads();
    int base = blockIdx.x * EPB;
#pragma unroll
    for (int it = 0; it < 16; ++it) {
        int e = base + it * 256 + tid;
        if (e < E) atomicAdd(&l[(unsigned)col[e] / (unsigned)span], 1);
    }
    __syncthreads();
    if (tid < 64 && l[tid]) atomicAdd(&rangecount[tid], l[tid]);
}

__global__ void k_rscan(const int* __restrict__ rangecount,
                        int* __restrict__ rangeoffs, int E) {
    __shared__ int s[64];
    int tid = threadIdx.x;  // one 64-thread block
    int v = rangecount[tid];
    s[tid] = v;
    __syncthreads();
    for (int d = 1; d < 64; d <<= 1) {
        int t = (tid >= d) ? s[tid - d] : 0;
        __syncthreads();
        s[tid] += t;
        __syncthreads();
    }
    rangeoffs[tid] = s[tid] - v;
    if (tid == 63) rangeoffs[64] = E;
}

// ---- phase A: bin edges into 64 destination ranges (write-amp ~1x) ----
__global__ void k_binA(const int* __restrict__ row, const int* __restrict__ col,
                       const int* __restrict__ rangeoffs, int* __restrict__ gcur,
                       uint2* __restrict__ staged, int E, int span) {
    __shared__ int lrun[64];
    int tid = threadIdx.x;
    int base = blockIdx.x * EPB;
    if (tid < 64) lrun[tid] = 0;
    __syncthreads();
#pragma unroll
    for (int it = 0; it < 16; ++it) {
        int e = base + it * 256 + tid;
        if (e < E) atomicAdd(&lrun[(unsigned)col[e] / (unsigned)span], 1);
    }
    __syncthreads();
    if (tid < 64) {
        int cnt = lrun[tid];
        int gb = cnt ? atomicAdd(&gcur[tid], cnt) : 0;
        lrun[tid] = rangeoffs[tid] + gb;  // absolute staged cursor for block+range
    }
    __syncthreads();
#pragma unroll
    for (int it = 0; it < 16; ++it) {
        int e = base + it * 256 + tid;
        if (e < E) {
            int c = col[e];
            int r = (unsigned)c / (unsigned)span;
            int pos = atomicAdd(&lrun[r], 1);
            staged[pos] = make_uint2((unsigned)c, (unsigned)row[e]);
        }
    }
}

// ---- phase B: per range: LDS node-hist -> in-block scan -> offs/dinv -> place ----
// Replaces the old global k_hist + k_dinv + 3 scan kernels entirely.
__global__ void k_binB(const uint2* __restrict__ staged, const int* __restrict__ rangeoffs,
                       int* __restrict__ offs, float* __restrict__ dinv,
                       int* __restrict__ srcarr, int N, int span) {
    __shared__ int lcnt[1600];
    __shared__ int partial[256];
    int r = blockIdx.x;
    int tid = threadIdx.x;
    int nstart = r * span;
    if (nstart >= N) return;
    int nend = nstart + span; if (nend > N) nend = N;
    int cnt = nend - nstart;
    int estart = rangeoffs[r], eend = rangeoffs[r + 1];
    for (int t = tid; t < cnt; t += 256) lcnt[t] = 0;
    __syncthreads();
    for (int e = estart + tid; e < eend; e += 256)
        atomicAdd(&lcnt[(int)staged[e].x - nstart], 1);
    __syncthreads();
    // chunked exclusive scan of lcnt[0..cnt)
    int chunk = (cnt + 255) / 256;
    int c0 = tid * chunk; if (c0 > cnt) c0 = cnt;
    int c1 = c0 + chunk;  if (c1 > cnt) c1 = cnt;
    int sum = 0;
    for (int t = c0; t < c1; ++t) sum += lcnt[t];
    partial[tid] = sum;
    __syncthreads();
    for (int d = 1; d < 256; d <<= 1) {
        int t = (tid >= d) ? partial[tid - d] : 0;
        __syncthreads();
        partial[tid] += t;
        __syncthreads();
    }
    int run = estart + partial[tid] - sum;  // global exclusive base for my chunk
    for (int t = c0; t < c1; ++t) {
        int c = lcnt[t];
        lcnt[t] = run;                       // becomes the placement cursor
        offs[nstart + t] = run;
        dinv[nstart + t] = rsqrtf(1.0f + (float)c);
        run += c;
    }
    if (nend == N && tid == 0) offs[N] = eend;  // == E
    __syncthreads();
    for (int e = estart + tid; e < eend; e += 256) {
        uint2 cr = staged[e];
        int idx = atomicAdd(&lcnt[(int)cr.x - nstart], 1);
        srcarr[idx] = (int)cr.y;
    }
}

// ------- input: h0 = relu(x @ W_in + b_in);  g = bf16(dinv * h0) -------
__global__ void k_in(const float* __restrict__ x, const float* __restrict__ Win,
                     const float* __restrict__ bin, const float* __restrict__ dinv,
                     float* __restrict__ h0, unsigned short* __restrict__ g, int N) {
    int lane = threadIdx.x & 63;
    int wave = (blockIdx.x * blockDim.x + threadIdx.x) >> 6;
    int nwaves = (gridDim.x * blockDim.x) >> 6;
    float wreg[17];
#pragma unroll
    for (int k = 0; k < 17; ++k) wreg[k] = Win[k * 64 + lane];
    float breg = bin[lane];
    for (int i = wave; i < N; i += nwaves) {
        float xv = (lane < 17) ? x[i * 17 + lane] : 0.0f;
        float acc = breg;
#pragma unroll
        for (int k = 0; k < 17; ++k) acc += readlane_f(xv, k) * wreg[k];
        float r = fmaxf(acc, 0.0f);
        h0[(size_t)i * 64 + lane] = r;
        g[(size_t)i * 64 + lane] = bf16_rtne(dinv[i] * r);
    }
}

// ---- fused gather+mix: per 16-node tile:
//   A[i] = dinv[i]*(sum_e g[src] + g[i])   (gathered into wave-private LDS)
//   out  = relu( c1*A + c2*h0 + bf16mfma([A|h0] @ [bW1;bW2]) )
// WRITE_G: out -> bf16 g' (prescaled by dinv) — MUST be a different buffer than gp
// (ping-pong), since reads of g are concurrent with writes of g'.
template <bool WRITE_G>
__global__ void k_gmix(const unsigned int* __restrict__ gp, const float* __restrict__ h0,
                       const float* __restrict__ W1, const float* __restrict__ W2,
                       const float* __restrict__ dinv, const int* __restrict__ offs,
                       const int* __restrict__ srcarr, float beta,
                       float* __restrict__ of32, unsigned short* __restrict__ og16,
                       int N) {
    __shared__ float atile_s[4][16][68];   // stride 68: 4-bank row step -> 2-way max
    int lane = threadIdx.x & 63;
    int wv = threadIdx.x >> 6;
    float (*atile)[68] = atile_s[wv];      // wave-private: no __syncthreads needed
    int p = lane & 31, s = lane >> 5;
    int wid = (blockIdx.x * blockDim.x + threadIdx.x) >> 6;
    int nw = (gridDim.x * blockDim.x) >> 6;
    float c1 = (1.0f - beta) * (1.0f - ALPHA_C);
    float c2 = (1.0f - beta) * ALPHA_C;

    bf16x8 bfrag[4][4];  // [col-tile][k-step], folded beta*W, resident in VGPRs
#pragma unroll
    for (int c = 0; c < 4; ++c) {
#pragma unroll
        for (int ks = 0; ks < 4; ++ks) {
            int n = c * 16 + (lane & 15);
            int kb = ks * 32 + (lane >> 4) * 8;
            bf16x8 f;
#pragma unroll
            for (int j = 0; j < 8; ++j) {
                int k = kb + j;
                float w = (k < 64) ? beta * W1[k * 64 + n]
                                   : beta * W2[(k - 64) * 64 + n];
                f[j] = (short)bf16_rtne(w);
            }
            bfrag[c][ks] = f;
        }
    }

    int ntiles = (N + 15) >> 4;
    for (int t = wid; t < ntiles; t += nw) {
        // ---- gather 16 node rows into LDS tile ----
        for (int ii = 0; ii < 16; ++ii) {
            int i = t * 16 + ii; if (i >= N) i = N - 1;
            int e0 = offs[i], e1 = offs[i + 1];
            float a0 = 0.0f, a1 = 0.0f;
            for (int base = e0 + s * 8; base < e1; base += 16) {
                int idx[8];
                unsigned v[8];
#pragma unroll
                for (int u = 0; u < 8; ++u) {
                    int ee = base + u;
                    idx[u] = srcarr[ee < e1 ? ee : e1 - 1];
                }
#pragma unroll
                for (int u = 0; u < 8; ++u) v[u] = gp[(size_t)idx[u] * 32 + p];
#pragma unroll
                for (int u = 0; u < 8; ++u) {
                    bool ok = (base + u < e1);
                    a0 += ok ? __uint_as_float(v[u] << 16) : 0.0f;
                    a1 += ok ? __uint_as_float(v[u] & 0xFFFF0000u) : 0.0f;
                }
            }
            a0 += __shfl_xor(a0, 32, 64);
            a1 += __shfl_xor(a1, 32, 64);
            unsigned sv = gp[(size_t)i * 32 + p];  // self-loop term
            a0 += __uint_as_float(sv << 16);
            a1 += __uint_as_float(sv & 0xFFFF0000u);
            if (s == 0) {
                float di = dinv[i];
                atile[ii][2 * p] = di * a0;
                atile[ii][2 * p + 1] = di * a1;
            }
        }
        // ---- MFMA: [A(LDS) | h0] @ bfrag ----
        int rl = lane & 15;
        int koff = (lane >> 4) * 8;
        int grow = t * 16 + rl; if (grow >= N) grow = N - 1;
        f32x4 acc[4];
#pragma unroll
        for (int c = 0; c < 4; ++c) acc[c] = (f32x4){0.f, 0.f, 0.f, 0.f};
#pragma unroll
        for (int ks = 0; ks < 4; ++ks) {
            const float* sp = (ks < 2)
                ? &atile[rl][ks * 32 + koff]
                : &h0[(size_t)grow * 64 + (ks - 2) * 32 + koff];
            f32x4 lo = *(const f32x4*)sp;
            f32x4 hi = *(const f32x4*)(sp + 4);
            bf16x8 af;
#pragma unroll
            for (int j = 0; j < 4; ++j) af[j] = (short)bf16_rtne(lo[j]);
#pragma unroll
            for (int j = 0; j < 4; ++j) af[4 + j] = (short)bf16_rtne(hi[j]);
#pragma unroll
            for (int c = 0; c < 4; ++c)
                acc[c] = __builtin_amdgcn_mfma_f32_16x16x32_bf16(af, bfrag[c][ks], acc[c], 0, 0, 0);
        }
        // ---- epilogue: f32 residual + relu ----
#pragma unroll
        for (int c = 0; c < 4; ++c) {
            int col = c * 16 + rl;
#pragma unroll
            for (int q = 0; q < 4; ++q) {
                int row16 = (lane >> 4) * 4 + q;
                int gr = t * 16 + row16;
                if (gr < N) {
                    float a = atile[row16][col];
                    size_t o = (size_t)gr * 64 + col;
                    float v = c1 * a + c2 * h0[o] + acc[c][q];
                    float rr = fmaxf(v, 0.0f);
                    if (WRITE_G) og16[o] = bf16_rtne(dinv[gr] * rr);
                    else         of32[o] = rr;
                }
            }
        }
    }
}

// ---------------- head: log_softmax(h @ W_out + b_out) ----------------
__global__ void k_out(const float* __restrict__ h, const float* __restrict__ Wout,
                      const float* __restrict__ bout, float* __restrict__ out, int N) {
    int lane = threadIdx.x & 63;
    int wave = (blockIdx.x * blockDim.x + threadIdx.x) >> 6;
    int nwaves = (gridDim.x * blockDim.x) >> 6;
    float w0 = Wout[lane * 2 + 0], w1 = Wout[lane * 2 + 1];
    float b0 = bout[0], b1 = bout[1];
    for (int i = wave; i < N; i += nwaves) {
        float hv = h[(size_t)i * 64 + lane];
        float p0 = hv * w0, p1 = hv * w1;
#pragma unroll
        for (int d = 32; d > 0; d >>= 1) {
            p0 += __shfl_xor(p0, d, 64);
            p1 += __shfl_xor(p1, d, 64);
        }
        if (lane == 0) {
            float c0 = p0 + b0, c1 = p1 + b1;
            float m = fmaxf(c0, c1);
            float lse = m + logf(expf(c0 - m) + expf(c1 - m));
            out[(size_t)i * 2 + 0] = c0 - lse;
            out[(size_t)i * 2 + 1] = c1 - lse;
        }
    }
}

extern "C" void kernel_launch(void* const* d_in, const int* in_sizes, int n_in,
                              void* d_out, int out_size, void* d_ws, size_t ws_size,
                              hipStream_t stream) {
    const float* x    = (const float*)d_in[0];
    const int*   ei   = (const int*)d_in[1];
    const float* Win  = (const float*)d_in[2];
    const float* bin  = (const float*)d_in[3];
    const float* W1   = (const float*)d_in[4];
    const float* W2   = (const float*)d_in[5];
    const float* Wout = (const float*)d_in[6];
    const float* bout = (const float*)d_in[7];
    float* out = (float*)d_out;

    const int N = in_sizes[0] / 17;
    const int E = in_sizes[1] / 2;
    const int* rowp = ei;
    const int* colp = ei + E;
    const int span = (N + 63) / 64;   // <= 1600 assumed (N <= 102400)

    char* p = (char*)d_ws;
    auto alloc = [&](size_t bytes) -> char* {
        char* r = p;
        p += (bytes + 255) & ~(size_t)255;
        return r;
    };
    int*   offs   = (int*)alloc((size_t)(N + 1) * sizeof(int));
    float* dinv   = (float*)alloc((size_t)N * sizeof(float));
    int*   rc_gc  = (int*)alloc(128 * sizeof(int));         // rangecount[64]+gcur[64]
    int*   roffs  = (int*)alloc(65 * sizeof(int));
    int*   srcarr = (int*)alloc((size_t)E * sizeof(int));
    size_t gbytes = (size_t)N * 64 * sizeof(unsigned short);
    size_t stbytes = (size_t)E * sizeof(uint2);
    char*  stg    = alloc(stbytes > gbytes ? stbytes : gbytes);  // staged, later gB
    float* h0     = (float*)alloc((size_t)N * 64 * sizeof(float));
    float* hfin   = (float*)alloc((size_t)N * 64 * sizeof(float));
    unsigned short* gA = (unsigned short*)alloc(gbytes);
    uint2*          staged = (uint2*)stg;
    unsigned short* gB     = (unsigned short*)stg;  // alias: staged dead after binB

    int* rangecount = rc_gc;
    int* gcur       = rc_gc + 64;
    hipMemsetAsync(rc_gc, 0, 128 * sizeof(int), stream);

    const int TB = 256;
    const int nbA = (E + EPB - 1) / EPB;

    k_rhist<<<nbA, TB, 0, stream>>>(colp, E, span, rangecount);
    k_rscan<<<1, 64, 0, stream>>>(rangecount, roffs, E);
    k_binA<<<nbA, TB, 0, stream>>>(rowp, colp, roffs, gcur, staged, E, span);
    k_binB<<<64, TB, 0, stream>>>(staged, roffs, offs, dinv, srcarr, N, span);

    k_in<<<2048, TB, 0, stream>>>(x, Win, bin, dinv, h0, gA, N);

    // ping-pong g buffers: L0 gA->gB, L1 gB->gA, L2 gA->gB, L3 gB->hfin(f32)
    for (int l = 0; l < 4; ++l) {
        float beta = logf(0.5f / (float)(l + 1) + 1.0f);
        const unsigned short* gin = (l & 1) ? gB : gA;
        unsigned short*       gout = (l & 1) ? gA : gB;
        if (l < 3)
            k_gmix<true><<<1024, TB, 0, stream>>>((const unsigned int*)gin, h0,
                                                  W1 + (size_t)l * 4096, W2 + (size_t)l * 4096,
                                                  dinv, offs, srcarr, beta,
                                                  nullptr, gout, N);
        else
            k_gmix<false><<<1024, TB, 0, stream>>>((const unsigned int*)gin, h0,
                                                   W1 + (size_t)l * 4096, W2 + (size_t)l * 4096,
                                                   dinv, offs, srcarr, beta,
                                                   hfin, nullptr, N);
    }
    k_out<<<1024, TB, 0, stream>>>(hfin, Wout, bout, out, N);
}

// Round 6
// 469.442 us; speedup vs baseline: 2.2593x; 1.0026x over previous
//
#include <hip/hip_runtime.h>
#include <math.h>

#define ALPHA_C 0.1f
#define EPB 4096  // edges per block in binning kernels (16 per thread)

typedef __attribute__((ext_vector_type(4))) float f32x4;
typedef __attribute__((ext_vector_type(8))) short bf16x8;

__device__ __forceinline__ float readlane_f(float v, int l) {
    return __int_as_float(__builtin_amdgcn_readlane(__float_as_int(v), l));
}

__device__ __forceinline__ unsigned short bf16_rtne(float f) {
    unsigned u = __float_as_uint(f);
    unsigned r = (u + 0x7FFFu + ((u >> 16) & 1u)) >> 16;
    return (unsigned short)r;
}

// ---- range histogram: 64 coarse bins (no 100k-wide random atomics) ----
__global__ void k_rhist(const int* __restrict__ col, int E, int span,
                        int* __restrict__ rangecount) {
    __shared__ int l[64];
    int tid = threadIdx.x;
    if (tid < 64) l[tid] = 0;
    __syncthreads();
    int base = blockIdx.x * EPB;
#pragma unroll
    for (int it = 0; it < 16; ++it) {
        int e = base + it * 256 + tid;
        if (e < E) atomicAdd(&l[(unsigned)col[e] / (unsigned)span], 1);
    }
    __syncthreads();
    if (tid < 64 && l[tid]) atomicAdd(&rangecount[tid], l[tid]);
}

__global__ void k_rscan(const int* __restrict__ rangecount,
                        int* __restrict__ rangeoffs, int E) {
    __shared__ int s[64];
    int tid = threadIdx.x;  // one 64-thread block
    int v = rangecount[tid];
    s[tid] = v;
    __syncthreads();
    for (int d = 1; d < 64; d <<= 1) {
        int t = (tid >= d) ? s[tid - d] : 0;
        __syncthreads();
        s[tid] += t;
        __syncthreads();
    }
    rangeoffs[tid] = s[tid] - v;
    if (tid == 63) rangeoffs[64] = E;
}

// ---- phase A: bin edges into 64 destination ranges (write-amp ~1x) ----
__global__ void k_binA(const int* __restrict__ row, const int* __restrict__ col,
                       const int* __restrict__ rangeoffs, int* __restrict__ gcur,
                       uint2* __restrict__ staged, int E, int span) {
    __shared__ int lrun[64];
    int tid = threadIdx.x;
    int base = blockIdx.x * EPB;
    if (tid < 64) lrun[tid] = 0;
    __syncthreads();
#pragma unroll
    for (int it = 0; it < 16; ++it) {
        int e = base + it * 256 + tid;
        if (e < E) atomicAdd(&lrun[(unsigned)col[e] / (unsigned)span], 1);
    }
    __syncthreads();
    if (tid < 64) {
        int cnt = lrun[tid];
        int gb = cnt ? atomicAdd(&gcur[tid], cnt) : 0;
        lrun[tid] = rangeoffs[tid] + gb;  // absolute staged cursor for block+range
    }
    __syncthreads();
#pragma unroll
    for (int it = 0; it < 16; ++it) {
        int e = base + it * 256 + tid;
        if (e < E) {
            int c = col[e];
            int r = (unsigned)c / (unsigned)span;
            int pos = atomicAdd(&lrun[r], 1);
            staged[pos] = make_uint2((unsigned)c, (unsigned)row[e]);
        }
    }
}

// ---- phase B: per range: LDS node-hist -> in-block scan -> offs/dinv -> place ----
// Replaces the old global k_hist + k_dinv + 3 scan kernels entirely.
__global__ void k_binB(const uint2* __restrict__ staged, const int* __restrict__ rangeoffs,
                       int* __restrict__ offs, float* __restrict__ dinv,
                       int* __restrict__ srcarr, int N, int span) {
    __shared__ int lcnt[1600];
    __shared__ int partial[256];
    int r = blockIdx.x;
    int tid = threadIdx.x;
    int nstart = r * span;
    if (nstart >= N) return;
    int nend = nstart + span; if (nend > N) nend = N;
    int cnt = nend - nstart;
    int estart = rangeoffs[r], eend = rangeoffs[r + 1];
    for (int t = tid; t < cnt; t += 256) lcnt[t] = 0;
    __syncthreads();
    for (int e = estart + tid; e < eend; e += 256)
        atomicAdd(&lcnt[(int)staged[e].x - nstart], 1);
    __syncthreads();
    // chunked exclusive scan of lcnt[0..cnt)
    int chunk = (cnt + 255) / 256;
    int c0 = tid * chunk; if (c0 > cnt) c0 = cnt;
    int c1 = c0 + chunk;  if (c1 > cnt) c1 = cnt;
    int sum = 0;
    for (int t = c0; t < c1; ++t) sum += lcnt[t];
    partial[tid] = sum;
    __syncthreads();
    for (int d = 1; d < 256; d <<= 1) {
        int t = (tid >= d) ? partial[tid - d] : 0;
        __syncthreads();
        partial[tid] += t;
        __syncthreads();
    }
    int run = estart + partial[tid] - sum;  // global exclusive base for my chunk
    for (int t = c0; t < c1; ++t) {
        int c = lcnt[t];
        lcnt[t] = run;                       // becomes the placement cursor
        offs[nstart + t] = run;
        dinv[nstart + t] = rsqrtf(1.0f + (float)c);
        run += c;
    }
    if (nend == N && tid == 0) offs[N] = eend;  // == E
    __syncthreads();
    for (int e = estart + tid; e < eend; e += 256) {
        uint2 cr = staged[e];
        int idx = atomicAdd(&lcnt[(int)cr.x - nstart], 1);
        srcarr[idx] = (int)cr.y;
    }
}

// ------- input: h0 = relu(x @ W_in + b_in);  g = bf16(dinv * h0) -------
__global__ void k_in(const float* __restrict__ x, const float* __restrict__ Win,
                     const float* __restrict__ bin, const float* __restrict__ dinv,
                     float* __restrict__ h0, unsigned short* __restrict__ g, int N) {
    int lane = threadIdx.x & 63;
    int wave = (blockIdx.x * blockDim.x + threadIdx.x) >> 6;
    int nwaves = (gridDim.x * blockDim.x) >> 6;
    float wreg[17];
#pragma unroll
    for (int k = 0; k < 17; ++k) wreg[k] = Win[k * 64 + lane];
    float breg = bin[lane];
    for (int i = wave; i < N; i += nwaves) {
        float xv = (lane < 17) ? x[i * 17 + lane] : 0.0f;
        float acc = breg;
#pragma unroll
        for (int k = 0; k < 17; ++k) acc += readlane_f(xv, k) * wreg[k];
        float r = fmaxf(acc, 0.0f);
        h0[(size_t)i * 64 + lane] = r;
        g[(size_t)i * 64 + lane] = bf16_rtne(dinv[i] * r);
    }
}

// ---- fused gather+mix: per 16-node tile:
//   A[i] = dinv[i]*(sum_e g[src] + g[i])   (gathered into wave-private LDS)
//   out  = relu( c1*A + c2*h0 + bf16mfma([A|h0] @ [bW1;bW2]) )
// WRITE_G: out -> bf16 g' (prescaled by dinv) — MUST be a different buffer than gp
// (ping-pong), since reads of g are concurrent with writes of g'.
template <bool WRITE_G>
__global__ void k_gmix(const unsigned int* __restrict__ gp, const float* __restrict__ h0,
                       const float* __restrict__ W1, const float* __restrict__ W2,
                       const float* __restrict__ dinv, const int* __restrict__ offs,
                       const int* __restrict__ srcarr, float beta,
                       float* __restrict__ of32, unsigned short* __restrict__ og16,
                       int N) {
    __shared__ float atile_s[4][16][68];   // stride 68: 4-bank row step -> 2-way max
    int lane = threadIdx.x & 63;
    int wv = threadIdx.x >> 6;
    float (*atile)[68] = atile_s[wv];      // wave-private: no __syncthreads needed
    int p = lane & 31, s = lane >> 5;
    int wid = (blockIdx.x * blockDim.x + threadIdx.x) >> 6;
    int nw = (gridDim.x * blockDim.x) >> 6;
    float c1 = (1.0f - beta) * (1.0f - ALPHA_C);
    float c2 = (1.0f - beta) * ALPHA_C;

    bf16x8 bfrag[4][4];  // [col-tile][k-step], folded beta*W, resident in VGPRs
#pragma unroll
    for (int c = 0; c < 4; ++c) {
#pragma unroll
        for (int ks = 0; ks < 4; ++ks) {
            int n = c * 16 + (lane & 15);
            int kb = ks * 32 + (lane >> 4) * 8;
            bf16x8 f;
#pragma unroll
            for (int j = 0; j < 8; ++j) {
                int k = kb + j;
                float w = (k < 64) ? beta * W1[k * 64 + n]
                                   : beta * W2[(k - 64) * 64 + n];
                f[j] = (short)bf16_rtne(w);
            }
            bfrag[c][ks] = f;
        }
    }

    int ntiles = (N + 15) >> 4;
    for (int t = wid; t < ntiles; t += nw) {
        // ---- gather 16 node rows into LDS tile ----
        for (int ii = 0; ii < 16; ++ii) {
            int i = t * 16 + ii; if (i >= N) i = N - 1;
            int e0 = offs[i], e1 = offs[i + 1];
            float a0 = 0.0f, a1 = 0.0f;
            for (int base = e0 + s * 8; base < e1; base += 16) {
                int idx[8];
                unsigned v[8];
#pragma unroll
                for (int u = 0; u < 8; ++u) {
                    int ee = base + u;
                    idx[u] = srcarr[ee < e1 ? ee : e1 - 1];
                }
#pragma unroll
                for (int u = 0; u < 8; ++u) v[u] = gp[(size_t)idx[u] * 32 + p];
#pragma unroll
                for (int u = 0; u < 8; ++u) {
                    bool ok = (base + u < e1);
                    a0 += ok ? __uint_as_float(v[u] << 16) : 0.0f;
                    a1 += ok ? __uint_as_float(v[u] & 0xFFFF0000u) : 0.0f;
                }
            }
            a0 += __shfl_xor(a0, 32, 64);
            a1 += __shfl_xor(a1, 32, 64);
            unsigned sv = gp[(size_t)i * 32 + p];  // self-loop term
            a0 += __uint_as_float(sv << 16);
            a1 += __uint_as_float(sv & 0xFFFF0000u);
            if (s == 0) {
                float di = dinv[i];
                atile[ii][2 * p] = di * a0;
                atile[ii][2 * p + 1] = di * a1;
            }
        }
        // ---- MFMA: [A(LDS) | h0] @ bfrag ----
        int rl = lane & 15;
        int koff = (lane >> 4) * 8;
        int grow = t * 16 + rl; if (grow >= N) grow = N - 1;
        f32x4 acc[4];
#pragma unroll
        for (int c = 0; c < 4; ++c) acc[c] = (f32x4){0.f, 0.f, 0.f, 0.f};
#pragma unroll
        for (int ks = 0; ks < 4; ++ks) {
            const float* sp = (ks < 2)
                ? &atile[rl][ks * 32 + koff]
                : &h0[(size_t)grow * 64 + (ks - 2) * 32 + koff];
            f32x4 lo = *(const f32x4*)sp;
            f32x4 hi = *(const f32x4*)(sp + 4);
            bf16x8 af;
#pragma unroll
            for (int j = 0; j < 4; ++j) af[j] = (short)bf16_rtne(lo[j]);
#pragma unroll
            for (int j = 0; j < 4; ++j) af[4 + j] = (short)bf16_rtne(hi[j]);
#pragma unroll
            for (int c = 0; c < 4; ++c)
                acc[c] = __builtin_amdgcn_mfma_f32_16x16x32_bf16(af, bfrag[c][ks], acc[c], 0, 0, 0);
        }
        // ---- epilogue: f32 residual + relu ----
#pragma unroll
        for (int c = 0; c < 4; ++c) {
            int col = c * 16 + rl;
#pragma unroll
            for (int q = 0; q < 4; ++q) {
                int row16 = (lane >> 4) * 4 + q;
                int gr = t * 16 + row16;
                if (gr < N) {
                    float a = atile[row16][col];
                    size_t o = (size_t)gr * 64 + col;
                    float v = c1 * a + c2 * h0[o] + acc[c][q];
                    float rr = fmaxf(v, 0.0f);
                    if (WRITE_G) og16[o] = bf16_rtne(dinv[gr] * rr);
                    else         of32[o] = rr;
                }
            }
        }
    }
}

// ---------------- head: log_softmax(h @ W_out + b_out) ----------------
__global__ void k_out(const float* __restrict__ h, const float* __restrict__ Wout,
                      const float* __restrict__ bout, float* __restrict__ out, int N) {
    int lane = threadIdx.x & 63;
    int wave = (blockIdx.x * blockDim.x + threadIdx.x) >> 6;
    int nwaves = (gridDim.x * blockDim.x) >> 6;
    float w0 = Wout[lane * 2 + 0], w1 = Wout[lane * 2 + 1];
    float b0 = bout[0], b1 = bout[1];
    for (int i = wave; i < N; i += nwaves) {
        float hv = h[(size_t)i * 64 + lane];
        float p0 = hv * w0, p1 = hv * w1;
#pragma unroll
        for (int d = 32; d > 0; d >>= 1) {
            p0 += __shfl_xor(p0, d, 64);
            p1 += __shfl_xor(p1, d, 64);
        }
        if (lane == 0) {
            float c0 = p0 + b0, c1 = p1 + b1;
            float m = fmaxf(c0, c1);
            float lse = m + logf(expf(c0 - m) + expf(c1 - m));
            out[(size_t)i * 2 + 0] = c0 - lse;
            out[(size_t)i * 2 + 1] = c1 - lse;
        }
    }
}

extern "C" void kernel_launch(void* const* d_in, const int* in_sizes, int n_in,
                              void* d_out, int out_size, void* d_ws, size_t ws_size,
                              hipStream_t stream) {
    const float* x    = (const float*)d_in[0];
    const int*   ei   = (const int*)d_in[1];
    const float* Win  = (const float*)d_in[2];
    const float* bin  = (const float*)d_in[3];
    const float* W1   = (const float*)d_in[4];
    const float* W2   = (const float*)d_in[5];
    const float* Wout = (const float*)d_in[6];
    const float* bout = (const float*)d_in[7];
    float* out = (float*)d_out;

    const int N = in_sizes[0] / 17;
    const int E = in_sizes[1] / 2;
    const int* rowp = ei;
    const int* colp = ei + E;
    const int span = (N + 63) / 64;   // <= 1600 assumed (N <= 102400)

    char* p = (char*)d_ws;
    auto alloc = [&](size_t bytes) -> char* {
        char* r = p;
        p += (bytes + 255) & ~(size_t)255;
        return r;
    };
    int*   offs   = (int*)alloc((size_t)(N + 1) * sizeof(int));
    float* dinv   = (float*)alloc((size_t)N * sizeof(float));
    int*   rc_gc  = (int*)alloc(128 * sizeof(int));         // rangecount[64]+gcur[64]
    int*   roffs  = (int*)alloc(65 * sizeof(int));
    int*   srcarr = (int*)alloc((size_t)E * sizeof(int));
    size_t gbytes = (size_t)N * 64 * sizeof(unsigned short);
    size_t stbytes = (size_t)E * sizeof(uint2);
    char*  stg    = alloc(stbytes > gbytes ? stbytes : gbytes);  // staged, later gB
    float* h0     = (float*)alloc((size_t)N * 64 * sizeof(float));
    float* hfin   = (float*)alloc((size_t)N * 64 * sizeof(float));
    unsigned short* gA = (unsigned short*)alloc(gbytes);
    uint2*          staged = (uint2*)stg;
    unsigned short* gB     = (unsigned short*)stg;  // alias: staged dead after binB

    int* rangecount = rc_gc;
    int* gcur       = rc_gc + 64;
    hipMemsetAsync(rc_gc, 0, 128 * sizeof(int), stream);

    const int TB = 256;
    const int nbA = (E + EPB - 1) / EPB;

    k_rhist<<<nbA, TB, 0, stream>>>(colp, E, span, rangecount);
    k_rscan<<<1, 64, 0, stream>>>(rangecount, roffs, E);
    k_binA<<<nbA, TB, 0, stream>>>(rowp, colp, roffs, gcur, staged, E, span);
    k_binB<<<64, TB, 0, stream>>>(staged, roffs, offs, dinv, srcarr, N, span);

    k_in<<<2048, TB, 0, stream>>>(x, Win, bin, dinv, h0, gA, N);

    // ping-pong g buffers: L0 gA->gB, L1 gB->gA, L2 gA->gB, L3 gB->hfin(f32)
    for (int l = 0; l < 4; ++l) {
        float beta = logf(0.5f / (float)(l + 1) + 1.0f);
        const unsigned short* gin = (l & 1) ? gB : gA;
        unsigned short*       gout = (l & 1) ? gA : gB;
        if (l < 3)
            k_gmix<true><<<1024, TB, 0, stream>>>((const unsigned int*)gin, h0,
                                                  W1 + (size_t)l * 4096, W2 + (size_t)l * 4096,
                                                  dinv, offs, srcarr, beta,
                                                  nullptr, gout, N);
        else
            k_gmix<false><<<1024, TB, 0, stream>>>((const unsigned int*)gin, h0,
                                                   W1 + (size_t)l * 4096, W2 + (size_t)l * 4096,
                                                   dinv, offs, srcarr, beta,
                                                   hfin, nullptr, N);
    }
    k_out<<<1024, TB, 0, stream>>>(hfin, Wout, bout, out, N);
}